// Round 4
// baseline (169.472 us; speedup 1.0000x reference)
//
#include <hip/hip_runtime.h>

// DigitCaps with O=1: routing softmax over one out-capsule is identity, so
// the reference reduces to
//   s[b,v]  = sum_{i,d} W[i,v,d] * x[b,i,d]        (M=32, N=512, K=32768 GEMM)
//   out     = s * sqrt(sq)/(1+sq),  sq = sum_v s^2  (per-b squash)
// Both tuple outputs (t, outputs) are identical [32,1,512] tensors.
//
// R4: R3's partial was W-LATENCY-bound (VALUBusy 17%; warm-L3 replays equally
// slow at 50.7us -> not BW-bound). Fix: 8-deep rolling register prefetch of W
// (1024 cyc cover vs ~900 cyc HBM latency), static slot indices via unrolled
// inner groups (no dynamic reg-array indexing -> no spill). x stays on the
// scalar pipe (block-uniform s_load with immediate offsets).

#define NB 32
#define NI 4096
#define NV 512
#define ND 8
#define XSTRIDE (NI * ND)   // floats per batch row of x
#define IC 32               // i's per chunk
#define NC (NI / IC)        // 128 chunks
#define NC8 (NC / 8)        // 16 second-stage groups
#define DEPTH 8             // W prefetch depth (iterations)
#define WSTEP (NV * ND / 4) // float4 stride per i-row of W

// ---------------------------------------------------------------------------
// Phase 1: partial[ic][b][v] = sum over i-chunk of W[i,v,:].x[b,i,:]
// Grid: bg(4) x vhalf(2) x ic(128) = 1024 blocks, 256 threads.
// Thread -> v = vh*256 + t, accumulates b = bg*8 .. bg*8+7.
// W: float4-pair per i, 8-deep rolling prefetch. x: s_load (scalar pipe).
// ---------------------------------------------------------------------------
__global__ __launch_bounds__(256) void caps_partial(
    const float* __restrict__ x, const float* __restrict__ W,
    float* __restrict__ partial)
{
    const int t  = threadIdx.x;
    const int bx = blockIdx.x;
    const int bg = bx & 3;
    const int vh = (bx >> 2) & 1;
    const int ic = bx >> 3;
    const int v  = vh * 256 + t;
    const int b0 = bg * 8;
    const int i0 = ic * IC;

    float acc[8];
#pragma unroll
    for (int b = 0; b < 8; ++b) acc[b] = 0.0f;

    // preload DEPTH i-rows of W into registers (2 float4 each)
    const float4* wp = (const float4*)(W + ((size_t)i0 * NV + v) * ND);
    float4 wbuf[DEPTH][2];
#pragma unroll
    for (int j = 0; j < DEPTH; ++j) {
        wbuf[j][0] = wp[0];
        wbuf[j][1] = wp[1];
        wp += WSTEP;
    }
    // wp now at row i0+DEPTH

    const float* xb = x + (size_t)b0 * XSTRIDE + (size_t)i0 * ND;

#define CAPS_BODY(j, REFILL)                                              \
    {                                                                     \
        const float4 cw0 = wbuf[j][0], cw1 = wbuf[j][1];                  \
        if (REFILL) {                                                     \
            wbuf[j][0] = wp[0];                                           \
            wbuf[j][1] = wp[1];                                           \
            wp += WSTEP;                                                  \
        }                                                                 \
        const float* xp = xb + (j) * ND;                                  \
        _Pragma("unroll")                                                 \
        for (int b = 0; b < 8; ++b) {                                     \
            const float* xq = xp + (size_t)b * XSTRIDE;  /* s_load imm */ \
            float a = acc[b];                                             \
            a = fmaf(cw0.x, xq[0], a);                                    \
            a = fmaf(cw0.y, xq[1], a);                                    \
            a = fmaf(cw0.z, xq[2], a);                                    \
            a = fmaf(cw0.w, xq[3], a);                                    \
            a = fmaf(cw1.x, xq[4], a);                                    \
            a = fmaf(cw1.y, xq[5], a);                                    \
            a = fmaf(cw1.z, xq[6], a);                                    \
            a = fmaf(cw1.w, xq[7], a);                                    \
            acc[b] = a;                                                   \
        }                                                                 \
    }

    // main groups with refill (prefetch distance = DEPTH iterations;
    // refilled rows are i0+DEPTH .. i0+IC-DEPTH-1+DEPTH < i0+IC: in bounds)
    for (int io = 0; io < IC / DEPTH - 1; ++io) {
#pragma unroll
        for (int j = 0; j < DEPTH; ++j)
            CAPS_BODY(j, true)
        xb += DEPTH * ND;
    }
    // epilogue group, no refill
#pragma unroll
    for (int j = 0; j < DEPTH; ++j)
        CAPS_BODY(j, false)

#undef CAPS_BODY

#pragma unroll
    for (int b = 0; b < 8; ++b)
        partial[((size_t)ic * NB + b0 + b) * NV + v] = acc[b];  // coalesced in v
}

// ---------------------------------------------------------------------------
// Phase 2a: tree reduce, 8 chunks -> 1.  Grid: NC8(16) x NB(32) = 512 blocks,
// 512 threads (one per v). 8 independent coalesced loads per thread (MLP).
// ---------------------------------------------------------------------------
__global__ __launch_bounds__(512) void caps_reduce8(
    const float* __restrict__ partial, float* __restrict__ partial2)
{
    const int v = threadIdx.x;
    const int b = blockIdx.x & 31;
    const int g = blockIdx.x >> 5;       // 0..NC8-1

    const float* p = partial + ((size_t)(g * 8) * NB + b) * NV + v;
    float s = 0.0f;
#pragma unroll
    for (int j = 0; j < 8; ++j)
        s += p[(size_t)j * NB * NV];

    partial2[((size_t)g * NB + b) * NV + v] = s;
}

// ---------------------------------------------------------------------------
// Phase 2b: final reduce over NC8 groups + squash + write both outputs.
// Grid: 32 blocks (one per b) x 512 threads (one per v).
// ---------------------------------------------------------------------------
__global__ __launch_bounds__(512) void caps_finish(
    const float* __restrict__ partial2, float* __restrict__ out)
{
    const int v = threadIdx.x;
    const int b = blockIdx.x;

    float s = 0.0f;
#pragma unroll
    for (int g = 0; g < NC8; ++g)        // 16 independent loads
        s += partial2[((size_t)g * NB + b) * NV + v];

    float sq = s * s;
#pragma unroll
    for (int off = 32; off > 0; off >>= 1)
        sq += __shfl_xor(sq, off, 64);

    __shared__ float red[8];
    if ((v & 63) == 0) red[v >> 6] = sq;
    __syncthreads();
    float tot = 0.0f;
#pragma unroll
    for (int wv = 0; wv < 8; ++wv) tot += red[wv];

    // squash factor: sq/((1+sq)*sqrt(sq)) == sqrt(sq)/(1+sq)
    const float factor = sqrtf(tot) / (1.0f + tot);
    const float r = s * factor;

    out[(size_t)b * NV + v]           = r;  // output 0: t       [B,1,V]
    out[NB * NV + (size_t)b * NV + v] = r;  // output 1: outputs [B,O,V]
}

extern "C" void kernel_launch(void* const* d_in, const int* in_sizes, int n_in,
                              void* d_out, int out_size, void* d_ws, size_t ws_size,
                              hipStream_t stream) {
    const float* x = (const float*)d_in[0];   // [32, 4096, 8]
    const float* W = (const float*)d_in[1];   // [1, 4096, 512, 8]
    float* out     = (float*)d_out;           // 2 x [32,1,512] concatenated

    float* partial  = (float*)d_ws;                       // 8 MB
    float* partial2 = partial + (size_t)NC * NB * NV;     // +1 MB (ws >= 16 MB)

    caps_partial<<<4 * 2 * NC, 256, 0, stream>>>(x, W, partial);
    caps_reduce8<<<NC8 * NB, 512, 0, stream>>>(partial, partial2);
    caps_finish<<<NB, 512, 0, stream>>>(partial2, out);
}

// Round 5
// 156.515 us; speedup vs baseline: 1.0828x; 1.0828x over previous
//
#include <hip/hip_runtime.h>

// DigitCaps with O=1: routing softmax over one out-capsule is identity, so
// the reference reduces to
//   s[b,v]  = sum_{i,d} W[i,v,d] * x[b,i,d]        (M=32, N=512, K=32768 GEMM)
//   out     = s * sqrt(sq)/(1+sq),  sq = sum_v s^2  (per-b squash)
// Both tuple outputs (t, outputs) are identical [32,1,512] tensors.
//
// R5: R3/R4 post-mortem showed (a) the compiler SINKS register prefetch of W
// back to first use (R3 VGPR_Count=20 < data held), (b) per-b s_load->FMA
// serial chains, (c) 2.2x W over-fetch because bg-siblings landed on
// different XCDs. Fixes:
//  - 8-row W sub-chunk (16 float4, 64 VGPR) where EVERY load's first use is
//    inside the first b-iteration -> compiler cannot sink; 16 loads batch.
//  - b outer / rows inner -> 64 consecutive scalar x floats per b: merged
//    s_load_dwordx8 runs, one lgkm wait per 64 FMAs.
//  - XCD swizzle: the 4 bg-siblings sharing a W tile get ids differing by 8
//    -> same XCD under round-robin dispatch -> L2 serves the redundancy.
//  - __launch_bounds__(256,4): VGPR cap 128 so the W buffer can't spill.

#define NB 32
#define NI 4096
#define NV 512
#define ND 8
#define XSTRIDE (NI * ND)   // floats per batch row of x
#define IC 32               // i's per block (= per chunk)
#define NC (NI / IC)        // 128 chunks
#define NC8 (NC / 8)        // 16 second-stage groups
#define SC 8                // i's per sub-chunk (W register buffer rows)
#define NSC (IC / SC)       // 4 sub-chunks
#define WSTEP (NV * ND / 4) // float4 stride per i-row of W

// ---------------------------------------------------------------------------
// Phase 1: partial[ic][b][v] = sum over i-chunk of W[i,v,:].x[b,i,:]
// Grid: 1024 blocks = bg(4) x vh(2) x icc(128), XCD-swizzled. 256 threads.
// Thread -> v = vh*256 + t, accumulates b = bg*8 .. bg*8+7.
// ---------------------------------------------------------------------------
__global__ __launch_bounds__(256, 4) void caps_partial(
    const float* __restrict__ x, const float* __restrict__ W,
    float* __restrict__ partial)
{
    const int t  = threadIdx.x;
    const int bx = blockIdx.x;
    // swizzle: ids of the 4 bg-siblings differ by 8 -> same (blockIdx % 8)
    // -> same XCD; launched within a 32-id window -> temporally co-resident.
    const int low3 = bx & 7;
    const int bg   = (bx >> 3) & 3;
    const int c    = bx >> 5;            // 0..31
    const int tile = c * 8 + low3;       // 0..255
    const int vh   = tile & 1;
    const int icc  = tile >> 1;          // 0..127

    const int v  = vh * 256 + t;
    const int b0 = bg * 8;
    const int i0 = icc * IC;

    float acc[8];
#pragma unroll
    for (int b = 0; b < 8; ++b) acc[b] = 0.0f;

    const float4* wbase = (const float4*)(W + ((size_t)i0 * NV + v) * ND);
    const float*  xbase = x + (size_t)b0 * XSTRIDE + (size_t)i0 * ND;

    for (int sc = 0; sc < NSC; ++sc) {
        // Load 8 W rows (16 independent float4 = 16 KB/wave in flight).
        // First b-iteration uses ALL of them -> loads cannot be sunk apart.
        float4 w[2 * SC];
#pragma unroll
        for (int r = 0; r < SC; ++r) {
            const float4* wp = wbase + (size_t)(sc * SC + r) * WSTEP;
            w[2 * r]     = wp[0];
            w[2 * r + 1] = wp[1];
        }

#pragma unroll
        for (int b = 0; b < 8; ++b) {
            // 64 consecutive floats, block-uniform -> merged s_load_dwordx8
            const float* xq = xbase + (size_t)b * XSTRIDE + sc * SC * ND;
            float a = acc[b];
#pragma unroll
            for (int r = 0; r < SC; ++r) {
                a = fmaf(w[2 * r].x,     xq[r * 8 + 0], a);
                a = fmaf(w[2 * r].y,     xq[r * 8 + 1], a);
                a = fmaf(w[2 * r].z,     xq[r * 8 + 2], a);
                a = fmaf(w[2 * r].w,     xq[r * 8 + 3], a);
                a = fmaf(w[2 * r + 1].x, xq[r * 8 + 4], a);
                a = fmaf(w[2 * r + 1].y, xq[r * 8 + 5], a);
                a = fmaf(w[2 * r + 1].z, xq[r * 8 + 6], a);
                a = fmaf(w[2 * r + 1].w, xq[r * 8 + 7], a);
            }
            acc[b] = a;
        }
    }

#pragma unroll
    for (int b = 0; b < 8; ++b)
        partial[((size_t)icc * NB + b0 + b) * NV + v] = acc[b];  // coalesced in v
}

// ---------------------------------------------------------------------------
// Phase 2a: tree reduce, 8 chunks -> 1.  Grid: NC8(16) x NB(32) = 512 blocks,
// 512 threads (one per v). 8 independent coalesced loads per thread (MLP).
// ---------------------------------------------------------------------------
__global__ __launch_bounds__(512) void caps_reduce8(
    const float* __restrict__ partial, float* __restrict__ partial2)
{
    const int v = threadIdx.x;
    const int b = blockIdx.x & 31;
    const int g = blockIdx.x >> 5;       // 0..NC8-1

    const float* p = partial + ((size_t)(g * 8) * NB + b) * NV + v;
    float s = 0.0f;
#pragma unroll
    for (int j = 0; j < 8; ++j)
        s += p[(size_t)j * NB * NV];

    partial2[((size_t)g * NB + b) * NV + v] = s;
}

// ---------------------------------------------------------------------------
// Phase 2b: final reduce over NC8 groups + squash + write both outputs.
// Grid: 32 blocks (one per b) x 512 threads (one per v).
// ---------------------------------------------------------------------------
__global__ __launch_bounds__(512) void caps_finish(
    const float* __restrict__ partial2, float* __restrict__ out)
{
    const int v = threadIdx.x;
    const int b = blockIdx.x;

    float s = 0.0f;
#pragma unroll
    for (int g = 0; g < NC8; ++g)        // 16 independent loads
        s += partial2[((size_t)g * NB + b) * NV + v];

    float sq = s * s;
#pragma unroll
    for (int off = 32; off > 0; off >>= 1)
        sq += __shfl_xor(sq, off, 64);

    __shared__ float red[8];
    if ((v & 63) == 0) red[v >> 6] = sq;
    __syncthreads();
    float tot = 0.0f;
#pragma unroll
    for (int wv = 0; wv < 8; ++wv) tot += red[wv];

    // squash factor: sq/((1+sq)*sqrt(sq)) == sqrt(sq)/(1+sq)
    const float factor = sqrtf(tot) / (1.0f + tot);
    const float r = s * factor;

    out[(size_t)b * NV + v]           = r;  // output 0: t       [B,1,V]
    out[NB * NV + (size_t)b * NV + v] = r;  // output 1: outputs [B,O,V]
}

extern "C" void kernel_launch(void* const* d_in, const int* in_sizes, int n_in,
                              void* d_out, int out_size, void* d_ws, size_t ws_size,
                              hipStream_t stream) {
    const float* x = (const float*)d_in[0];   // [32, 4096, 8]
    const float* W = (const float*)d_in[1];   // [1, 4096, 512, 8]
    float* out     = (float*)d_out;           // 2 x [32,1,512] concatenated

    float* partial  = (float*)d_ws;                       // 8 MB
    float* partial2 = partial + (size_t)NC * NB * NV;     // +1 MB (ws >= 16 MB)

    caps_partial<<<4 * 2 * NC, 256, 0, stream>>>(x, W, partial);
    caps_reduce8<<<NC8 * NB, 512, 0, stream>>>(partial, partial2);
    caps_finish<<<NB, 512, 0, stream>>>(partial2, out);
}